// Round 1
// baseline (54.750 us; speedup 1.0000x reference)
//
#include <hip/hip_runtime.h>
#include <hip/hip_bf16.h>

// Analytic reduction of the circuit:
//   out[b,w] = prod_{v=0..w} cos(inputs[b,v])
// rz_params cancels in |amplitude|^2 (RZ is diagonal phase; CNOT chain is a
// classical basis permutation; qubits are independent Bernoulli before it).
//
// B=8192, n=10. One thread per batch row; cumprod of cos over 10 elements.

#ifndef NWIRES
#define NWIRES 10
#endif

__global__ __launch_bounds__(256) void quantum_cumcos_kernel(
    const float* __restrict__ inputs,  // (B, n) row-major
    float* __restrict__ out,           // (B, n)
    int B)
{
    int b = blockIdx.x * blockDim.x + threadIdx.x;
    if (b >= B) return;

    const float* row = inputs + (size_t)b * NWIRES;
    float* orow = out + (size_t)b * NWIRES;

    float acc = 1.0f;
#pragma unroll
    for (int w = 0; w < NWIRES; ++w) {
        acc *= __cosf(row[w]);
        orow[w] = acc;
    }
}

extern "C" void kernel_launch(void* const* d_in, const int* in_sizes, int n_in,
                              void* d_out, int out_size, void* d_ws, size_t ws_size,
                              hipStream_t stream) {
    const float* inputs = (const float*)d_in[0];   // (B, n) float32
    // d_in[1] = rz_params — provably irrelevant to the output.
    float* out = (float*)d_out;

    const int n = NWIRES;
    const int B = in_sizes[0] / n;   // 8192

    const int block = 256;
    const int grid = (B + block - 1) / block;
    quantum_cumcos_kernel<<<grid, block, 0, stream>>>(inputs, out, B);
}